// Round 10
// baseline (70.761 us; speedup 1.0000x reference)
//
#include <hip/hip_runtime.h>

// MotionResidualBranch — collapsed-linear formulation, ONE regular kernel.
//
// Pipeline is linear in 15 per-(b,t) scalars. Folded tables:
//   Gt[o][e], o=j*16+i: conv-tap j x {mfold_i (i<15), WM_b path (i==15)}
//   folded through pw_w;  base[e];
//   coef row (16 floats): 15 scalars + validity flag (0 on pad rows):
//   U_pw[b,t,e] = base[e] + sum_{j,i} coef[t-1+j, i]*Gt[j*16+i][e]  + LN.
//
// r9 post-mortem: sync scheme correct, but the allocator chose VGPR=44 and
// spilled Gr[48]+acc[16] (3rd fused kernel in a row at ~40 VGPR). Fix:
// amdgpu_waves_per_eu(2,2) pins occupancy at exactly 2 waves/EU so the
// allocator has no incentive to save registers (budget 256 VGPR).
// Co-residency for the flag-spin still holds: 2 blocks/CU * 256 CU = 512.

#define DD 256
#define KK 54
#define BB 8
#define TT 1024
#define NCOEF 15
#define CROW 16            // coef row: 15 scalars + validity
#define TS 16              // t-strip per block
#define NROWS (TS + 2)     // halo rows per block
#define NPROD 49
#define MAGIC 0x5EED1234u

__global__
__attribute__((amdgpu_flat_work_group_size(256, 256), amdgpu_waves_per_eu(2, 2)))
void fused1(
    const float* __restrict__ barX, const float* __restrict__ W,
    const float* __restrict__ phi_v_w, const float* __restrict__ phi_v_b,
    const float* __restrict__ phi_a_w, const float* __restrict__ phi_a_b,
    const float* __restrict__ gamma_v, const float* __restrict__ gamma_a,
    const float* __restrict__ WM_w, const float* __restrict__ WM_b,
    const float* __restrict__ dw_w, const float* __restrict__ dw_b,
    const float* __restrict__ pw_w, const float* __restrict__ pw_b,
    const float* __restrict__ ln_w, const float* __restrict__ ln_b,
    float* __restrict__ Gt, float* __restrict__ baset,
    unsigned* __restrict__ flags, float* __restrict__ cscratch,
    float* __restrict__ out)
{
  const int g    = blockIdx.x;          // 512 blocks
  const int tid  = threadIdx.x;
  const int wave = tid >> 6, lane = tid & 63;
  const int b    = g >> 6;
  const int t0   = (g & 63) * TS;

  __shared__ __align__(16) float sA[DD];
  __shared__ __align__(16) float sB[DD];
  __shared__ float wsl[4][64 * 5];
  __shared__ float aT[TS][DD + 1];
  __shared__ float musd[TS][2];

  // ---------------- A: producers (blocks 0..48) -> table column ----------------
  if (g < NPROD) {
    const int o = g;
    float cv;
    if (o < 48) {
      const int j = o >> 4, i = o & 15;
      if (i < 15) {
        const int p = i / 5, q = i - p * 5;
        float v;
        if (q == 4) v = gamma_v[0] * phi_v_b[tid] + gamma_a[0] * phi_a_b[tid];
        else { const float* phi = (q < 2) ? phi_v_w : phi_a_w; v = phi[tid * 2 + (q & 1)]; }
        sA[tid] = v;
        __syncthreads();
        const float4* wrow = (const float4*)(WM_w + (size_t)tid * (3 * DD) + p * DD);
        const float4* ph   = (const float4*)sA;
        float m = 0.f;
#pragma unroll 8
        for (int c = 0; c < DD / 4; ++c) {
          const float4 a = wrow[c], bq = ph[c];
          m += a.x * bq.x + a.y * bq.y + a.z * bq.z + a.w * bq.w;
        }
        cv = dw_w[tid * 3 + j] * m;
      } else {
        cv = dw_w[tid * 3 + j] * WM_b[tid];
      }
    } else {
      cv = dw_b[tid];
    }
    sB[tid] = cv;
    __syncthreads();
    const float4* prow = (const float4*)(pw_w + (size_t)tid * DD);
    const float4* cp   = (const float4*)sB;
    float acc = 0.f;
#pragma unroll 8
    for (int c = 0; c < DD / 4; ++c) {
      const float4 a = prow[c], bq = cp[c];
      acc += a.x * bq.x + a.y * bq.y + a.z * bq.z + a.w * bq.w;
    }
    if (o < 48)
      __hip_atomic_store(&Gt[o * DD + tid], acc, __ATOMIC_RELAXED, __HIP_MEMORY_SCOPE_AGENT);
    else
      __hip_atomic_store(&baset[tid], acc + pw_b[tid], __ATOMIC_RELAXED, __HIP_MEMORY_SCOPE_AGENT);
    __threadfence();                    // agent release (writeback)
    __syncthreads();
    if (tid == 0)
      __hip_atomic_store(&flags[o], MAGIC, __ATOMIC_RELEASE, __HIP_MEMORY_SCOPE_AGENT);
  }

  // ---------------- B: coef halo rows (all blocks, local) ----------------
  // row r (0..17) <-> time t0-1+r; wave w computes rows w, w+4, w+8, w+12, w+16.
  const float gv = gamma_v[0], ga = gamma_a[0];
  float rowv[5];
#pragma unroll
  for (int k = 0; k < 5; ++k) rowv[k] = 0.f;
  float* lds = wsl[wave];
#pragma unroll
  for (int k = 0; k < 5; ++k) {
    const int r = wave + 4 * k;
    if (r < NROWS) {
      const int t = t0 - 1 + r;
      if (t >= 0 && t < TT) {           // wave-uniform; pad rows stay 0
        const int bt = b * TT + t;
        float w = 0.f, v0 = 0.f, v1 = 0.f, a0 = 0.f, a1 = 0.f;
        if (lane < KK) {
          w = W[(size_t)bt * KK + lane];
          const float2* xp = (const float2*)barX + ((size_t)bt * KK + lane);
          const float2 x = xp[0];
          float2 xm = make_float2(0.f, 0.f), xmm = make_float2(0.f, 0.f);
          if (t >= 1) xm  = xp[-KK];
          if (t >= 2) xmm = xp[-2 * KK];
          v0 = x.x - xm.x; v1 = x.y - xm.y;
          const float vm0 = (t >= 1) ? (xm.x - xmm.x) : 0.f;
          const float vm1 = (t >= 1) ? (xm.y - xmm.y) : 0.f;
          a0 = v0 - vm0; a1 = v1 - vm1;
        }
        float wsum = w;
#pragma unroll
        for (int m = 32; m; m >>= 1) wsum += __shfl_xor(wsum, m);
        const float wn = w * (1.f / (wsum + 1e-6f));
        lds[lane * 5 + 0] = wn * v0; lds[lane * 5 + 1] = wn * v1;
        lds[lane * 5 + 2] = wn * a0; lds[lane * 5 + 3] = wn * a1;
        lds[lane * 5 + 4] = wn;
        // wave-synchronous gather (only this wave touches wsl[wave])
        if (lane < CROW) {
          float accv;
          if (lane == NCOEF) {
            accv = 1.0f;               // validity flag -> H term
          } else {
            const int p = lane / 5, q = lane - p * 5;
            const int k0 = (p == 0) ? 0  : ((p == 1) ? 12 : 33);
            const int k1 = (p == 0) ? 12 : ((p == 1) ? 33 : 54);
            accv = 0.f;
            for (int kk = k0; kk < k1; ++kk) accv += lds[kk * 5 + q];
            if (q < 2) accv *= gv; else if (q < 4) accv *= ga;
          }
          rowv[k] = accv;
        }
      }
    }
  }

  // ---------------- C: wait for tables, acquire ----------------
  if (tid < NPROD) {
    int it = 0;
    while (__hip_atomic_load(&flags[tid], __ATOMIC_ACQUIRE, __HIP_MEMORY_SCOPE_AGENT)
               != MAGIC && it < (1 << 23)) {
      ++it;
      __builtin_amdgcn_s_sleep(8);
    }
  }
  __syncthreads();
  __threadfence();                     // agent acquire (invalidate stale lines)

  // ---------------- D: coef rows -> block-private scratch (for s_load) ----------------
  float* myscr = cscratch + (size_t)g * (NROWS * CROW);
  if (lane < CROW) {
#pragma unroll
    for (int k = 0; k < 5; ++k) {
      const int r = wave + 4 * k;
      if (r < NROWS) myscr[r * CROW + lane] = rowv[k];
    }
  }
  __syncthreads();                     // drains vmcnt -> L2; s_load sees it

  // ---------------- E/F: 48-FMA main loop (scalar coef operands) ----------------
  float Gr[48];
#pragma unroll
  for (int o = 0; o < 48; ++o)
    Gr[o] = __hip_atomic_load(&Gt[o * DD + tid], __ATOMIC_RELAXED, __HIP_MEMORY_SCOPE_AGENT);
  const float bs = __hip_atomic_load(&baset[tid], __ATOMIC_RELAXED, __HIP_MEMORY_SCOPE_AGENT);
  const float lw = ln_w[tid], lb = ln_b[tid];

  float acc[TS];
#pragma unroll
  for (int tl = 0; tl < TS; ++tl) acc[tl] = bs;

  const int rowbase = g * (NROWS * CROW);
#pragma unroll
  for (int r = 0; r < NROWS; ++r) {
    const int off = __builtin_amdgcn_readfirstlane(rowbase + r * CROW);
    const float* cr = cscratch + off;  // SGPR (scalar) loads, K$/L2-resident
    const int tlo = (r - 2 > 0) ? (r - 2) : 0;
    const int thi = (r < TS - 1) ? r : (TS - 1);
#pragma unroll
    for (int tl = tlo; tl <= thi; ++tl) {
      const int j = r - tl;            // 0..2, compile-time after unroll
#pragma unroll
      for (int i = 0; i < CROW; ++i)
        acc[tl] += cr[i] * Gr[j * CROW + i];
    }
  }

  // ---------------- G: LayerNorm via one LDS transpose ----------------
#pragma unroll
  for (int tl = 0; tl < TS; ++tl) aT[tl][tid] = acc[tl];
  __syncthreads();
  {
    const int tg = tid >> 4, grp = tid & 15;
    float s = 0.f, ss = 0.f;
#pragma unroll
    for (int k = 0; k < 16; ++k) {
      const float v = aT[tg][grp * 16 + ((k + grp) & 15)];
      s += v; ss += v * v;
    }
#pragma unroll
    for (int m = 8; m; m >>= 1) { s += __shfl_xor(s, m); ss += __shfl_xor(ss, m); }
    if (grp == 0) {
      const float mu  = s * (1.f / DD);
      const float var = ss * (1.f / DD) - mu * mu;
      musd[tg][0] = mu;
      musd[tg][1] = rsqrtf(var + 1e-5f);
    }
  }
  __syncthreads();
#pragma unroll
  for (int tl = 0; tl < TS; ++tl) {
    const float mu = musd[tl][0], rs = musd[tl][1];
    out[((size_t)b * TT + t0 + tl) * DD + tid] = (acc[tl] - mu) * rs * lw + lb;
  }
}

extern "C" void kernel_launch(void* const* d_in, const int* in_sizes, int n_in,
                              void* d_out, int out_size, void* d_ws, size_t ws_size,
                              hipStream_t stream) {
  const float* barX    = (const float*)d_in[0];
  const float* W       = (const float*)d_in[1];
  const float* phi_v_w = (const float*)d_in[2];
  const float* phi_v_b = (const float*)d_in[3];
  const float* phi_a_w = (const float*)d_in[4];
  const float* phi_a_b = (const float*)d_in[5];
  const float* gamma_v = (const float*)d_in[6];
  const float* gamma_a = (const float*)d_in[7];
  const float* WM_w    = (const float*)d_in[8];
  const float* WM_b    = (const float*)d_in[9];
  const float* dw_w    = (const float*)d_in[10];
  const float* dw_b    = (const float*)d_in[11];
  const float* pw_w    = (const float*)d_in[12];
  const float* pw_b    = (const float*)d_in[13];
  const float* ln_w    = (const float*)d_in[14];
  const float* ln_b    = (const float*)d_in[15];
  float* out = (float*)d_out;

  float* ws        = (float*)d_ws;
  float* Gt        = ws;                // 48*256 = 12288 floats
  float* baset     = ws + 12288;        // 256
  unsigned* flags  = (unsigned*)(ws + 12544);  // 49 u32 (pad to 16384)
  float* cscratch  = ws + 16384;        // 512*18*16 = 147456 floats
  // total ~655 KB of d_ws

  hipLaunchKernelGGL(fused1, dim3(BB * (TT / TS)), dim3(256), 0, stream,
                     barX, W, phi_v_w, phi_v_b, phi_a_w, phi_a_b,
                     gamma_v, gamma_a, WM_w, WM_b, dw_w, dw_b, pw_w, pw_b,
                     ln_w, ln_b, Gt, baset, flags, cscratch, out);
}

// Round 11
// 63.222 us; speedup vs baseline: 1.1192x; 1.1192x over previous
//
#include <hip/hip_runtime.h>

// MotionResidualBranch — collapsed-linear formulation, 2 kernels (r8 skeleton).
//
// Pipeline is linear in 15 per-(b,t) scalars. Folded tables:
//   Gt[o][e], o=j*16+i: conv-tap j x {mfold_i (i<15), WM_b path (i==15)}
//   folded through pw_w; base[e]. coef row = 15 scalars + validity flag.
//   U_pw[b,t,e] = base[e] + sum_{j,i} coef[t-1+j,i]*Gt[j*16+i][e]  + LN.
//
// r10 post-mortem: fused/spin variants have an invisible ~60us stall (4/4
// attempts); 2-kernel chain is the proven structure (30.7us). This round
// fixes the last bad access pattern: table blocks now use coalesced LDS
// staging + conflict-free LDS dots (16 blocks) instead of thread-per-e
// strided dots (64-line fan per wave instr).

#define DD 256
#define KK 54
#define BB 8
#define TT 1024
#define NCOEF 15
#define CROW 16          // padded coef row (64B)
#define TROWS (TT + 2)   // zero row before t=0 and after t=TT-1
#define TS 16
#define NBT (BB * TT)
#define NTB 16           // table blocks

// LDS layout (floats) for ka — manually unioned:
//   wmT   [32][260] @ 0      (8320)   | pwL [16][257] aliases @0 (4112)
//   phiL  [5][256]  @ 8320   (1280)   | coef-path wsl aliases @0 (1280)
//   mfoldL[16][257] @ 9600   (4112)
//   dwf   [768]     @ 13712
//   dwb   [256]     @ 14480
//   partial[8][32][5] @ 14736 (1280)  -> total 16016 floats = 64.1 KB
#define SM_WMT   0
#define SM_PHI   8320
#define SM_MF    9600
#define SM_DWF   13712
#define SM_DWB   14480
#define SM_PART  14736
#define SM_TOTAL 16016

// ---------- K_A: blocks 0..15 -> tables ; blocks 16..527 -> coef ----------
__global__ __launch_bounds__(256) void ka_tables_coef(
    const float* __restrict__ barX, const float* __restrict__ W,
    const float* __restrict__ phi_v_w, const float* __restrict__ phi_v_b,
    const float* __restrict__ phi_a_w, const float* __restrict__ phi_a_b,
    const float* __restrict__ gamma_v, const float* __restrict__ gamma_a,
    const float* __restrict__ WM_w, const float* __restrict__ WM_b,
    const float* __restrict__ dw_w, const float* __restrict__ dw_b,
    const float* __restrict__ pw_w, const float* __restrict__ pw_b,
    float* __restrict__ Gt, float* __restrict__ baset, float* __restrict__ coef)
{
  const int tid  = threadIdx.x;
  const int wave = tid >> 6, lane = tid & 63;
  __shared__ __align__(16) float smem[SM_TOTAL];

  if (blockIdx.x < NTB) {
    // ================= table block tb: owns e in [tb*16, tb*16+16) =========
    const int tb = blockIdx.x;
    const float gv = gamma_v[0], ga = gamma_a[0];
    // ---- phase 0: stage phi / dw / WM_b ----
    {
      const int c = tid;
      const float2 fv = *(const float2*)(phi_v_w + 2 * c);
      const float2 fa = *(const float2*)(phi_a_w + 2 * c);
      smem[SM_PHI + 0 * 256 + c] = fv.x;
      smem[SM_PHI + 1 * 256 + c] = fv.y;
      smem[SM_PHI + 2 * 256 + c] = fa.x;
      smem[SM_PHI + 3 * 256 + c] = fa.y;
      smem[SM_PHI + 4 * 256 + c] = gv * phi_v_b[c] + ga * phi_a_b[c];
      smem[SM_DWF + c]       = dw_w[c];
      smem[SM_DWF + 256 + c] = dw_w[256 + c];
      smem[SM_DWF + 512 + c] = dw_w[512 + c];
      smem[SM_DWB + c] = dw_b[c];
      smem[SM_MF + 15 * 257 + c] = WM_b[c];     // mfold row 15 = WM_b path
    }
    __syncthreads();
    // ---- phase 1: mfold[p*5+q][d] = sum_c phi_q[c] * WM_w[d][p*256+c] ----
    const int cg = tid >> 5, dl = tid & 31;     // c-group 0..7, d-lane 0..31
    for (int p = 0; p < 3; ++p) {
      for (int tile = 0; tile < 8; ++tile) {
        // stage 32 d-rows x 256 c (coalesced: one wave per row-quarter)
#pragma unroll
        for (int k = 0; k < 8; ++k) {
          const int row = k * 4 + (tid >> 6);
          const int col = (tid & 63) * 4;
          *(float4*)&smem[SM_WMT + row * 260 + col] =
              *(const float4*)&WM_w[(size_t)(tile * 32 + row) * 768 + p * 256 + col];
        }
        __syncthreads();
        float s0 = 0.f, s1 = 0.f, s2 = 0.f, s3 = 0.f, s4 = 0.f;
#pragma unroll
        for (int k4 = 0; k4 < 8; ++k4) {
          const int cbase = cg * 32 + k4 * 4;
          const float4 wv = *(const float4*)&smem[SM_WMT + dl * 260 + cbase];
          const float4 p0 = *(const float4*)&smem[SM_PHI + 0 * 256 + cbase];
          const float4 p1 = *(const float4*)&smem[SM_PHI + 1 * 256 + cbase];
          const float4 p2 = *(const float4*)&smem[SM_PHI + 2 * 256 + cbase];
          const float4 p3 = *(const float4*)&smem[SM_PHI + 3 * 256 + cbase];
          const float4 p4 = *(const float4*)&smem[SM_PHI + 4 * 256 + cbase];
          s0 += wv.x * p0.x + wv.y * p0.y + wv.z * p0.z + wv.w * p0.w;
          s1 += wv.x * p1.x + wv.y * p1.y + wv.z * p1.z + wv.w * p1.w;
          s2 += wv.x * p2.x + wv.y * p2.y + wv.z * p2.z + wv.w * p2.w;
          s3 += wv.x * p3.x + wv.y * p3.y + wv.z * p3.z + wv.w * p3.w;
          s4 += wv.x * p4.x + wv.y * p4.y + wv.z * p4.z + wv.w * p4.w;
        }
        float* pr = &smem[SM_PART + (cg * 32 + dl) * 5];
        pr[0] = s0; pr[1] = s1; pr[2] = s2; pr[3] = s3; pr[4] = s4;
        __syncthreads();
        if (tid < 160) {
          const int q = tid >> 5, dl2 = tid & 31;
          float m = 0.f;
#pragma unroll
          for (int c2 = 0; c2 < 8; ++c2) m += smem[SM_PART + (c2 * 32 + dl2) * 5 + q];
          smem[SM_MF + (p * 5 + q) * 257 + tile * 32 + dl2] = m;
        }
        __syncthreads();                         // before next stage overwrites wmT
      }
    }
    // ---- phase 2: stage 16 pw rows (alias over wmT), accumulate Gt ----
#pragma unroll
    for (int k = 0; k < 4; ++k) {
      const int r = k * 4 + (tid >> 6);
      const int col = (tid & 63) * 4;
      *(float4*)&smem[SM_WMT + r * 257 + col] =    // pwL[r][col], pad 257
          *(const float4*)&pw_w[(size_t)(tb * 16 + r) * 256 + col];
    }
    __syncthreads();
    {
      const int el = tid >> 4, og = tid & 15;
      float g0 = 0.f, g1 = 0.f, g2 = 0.f, g3 = 0.f;
      for (int d = 0; d < 256; ++d) {
        const float pw = smem[SM_WMT + el * 257 + d];
        const float mf = smem[SM_MF + og * 257 + d];
        const float pm = pw * mf;
        g0 = fmaf(pm, smem[SM_DWF + d * 3 + 0], g0);
        g1 = fmaf(pm, smem[SM_DWF + d * 3 + 1], g1);
        g2 = fmaf(pm, smem[SM_DWF + d * 3 + 2], g2);
        if (og == 0) g3 = fmaf(pw, smem[SM_DWB + d], g3);
      }
      const int e = tb * 16 + el;
      Gt[(0 * 16 + og) * DD + e] = g0;
      Gt[(1 * 16 + og) * DD + e] = g1;
      Gt[(2 * 16 + og) * DD + e] = g2;
      if (og == 0) baset[e] = g3 + pw_b[e];
    }
  } else {
    // ================= coef: 16 rows per block, 4 rounds of 4 waves ========
    const int blk  = blockIdx.x - NTB;      // 0..511
    const int base = blk * 16;
    const float gv = gamma_v[0], ga = gamma_a[0];
    float* lds = &smem[wave * 320];         // wave-local 64x5 slice @ offset 0
    for (int r = 0; r < 4; ++r) {
      const int bt = base + r * 4 + wave;
      const int t  = bt & (TT - 1);
      const int b  = bt >> 10;
      float w = 0.f, v0 = 0.f, v1 = 0.f, a0 = 0.f, a1 = 0.f;
      if (lane < KK) {
        w = W[(size_t)bt * KK + lane];
        const float2* xp = (const float2*)barX + ((size_t)bt * KK + lane);
        const float2 x = xp[0];
        float2 xm = make_float2(0.f, 0.f), xmm = make_float2(0.f, 0.f);
        if (t >= 1) xm  = xp[-KK];
        if (t >= 2) xmm = xp[-2 * KK];
        v0 = x.x - xm.x; v1 = x.y - xm.y;
        const float vm0 = (t >= 1) ? (xm.x - xmm.x) : 0.f;
        const float vm1 = (t >= 1) ? (xm.y - xmm.y) : 0.f;
        a0 = v0 - vm0; a1 = v1 - vm1;
      }
      float wsum = w;
#pragma unroll
      for (int m = 32; m; m >>= 1) wsum += __shfl_xor(wsum, m);
      const float wn = w * (1.f / (wsum + 1e-6f));
      lds[lane * 5 + 0] = wn * v0; lds[lane * 5 + 1] = wn * v1;
      lds[lane * 5 + 2] = wn * a0; lds[lane * 5 + 3] = wn * a1;
      lds[lane * 5 + 4] = wn;
      // wave-synchronous LDS (only this wave touches its slice)
      if (lane < CROW) {
        float accv;
        if (lane == NCOEF) {
          accv = 1.0f;                      // validity flag -> H term
        } else {
          const int p = lane / 5, q = lane - p * 5;
          const int k0 = (p == 0) ? 0  : ((p == 1) ? 12 : 33);
          const int k1 = (p == 0) ? 12 : ((p == 1) ? 33 : 54);
          accv = 0.f;
          for (int k = k0; k < k1; ++k) accv += lds[k * 5 + q];
          if (q < 2) accv *= gv; else if (q < 4) accv *= ga;
        }
        coef[((size_t)b * TROWS + 1 + t) * CROW + lane] = accv;
      }
    }
    // zero pad rows: first 16 coef-blocks each write one
    if (blk < 2 * BB && tid < CROW) {
      const int b = blk >> 1, side = blk & 1;
      coef[((size_t)b * TROWS + (side ? (TT + 1) : 0)) * CROW + tid] = 0.f;
    }
  }
}

// ---------- K_B: row-centric 48-FMA (scalar operands) + transposed LN ----------
__global__ __launch_bounds__(256, 1) void kb_main(
    const float* __restrict__ coef, const float* __restrict__ Gt,
    const float* __restrict__ baset, const float* __restrict__ ln_w,
    const float* __restrict__ ln_b, float* __restrict__ out)
{
  const int b  = blockIdx.x >> 6;
  const int t0 = (blockIdx.x & 63) * TS;
  const int e  = threadIdx.x;

  float Gr[48];
#pragma unroll
  for (int o = 0; o < 48; ++o) Gr[o] = Gt[o * DD + e];
  const float bs = baset[e];
  const float lw = ln_w[e], lb = ln_b[e];

  float acc[TS];
#pragma unroll
  for (int tl = 0; tl < TS; ++tl) acc[tl] = bs;

  const int rowbase = (b * TROWS + t0) * CROW;
#pragma unroll
  for (int r = 0; r < TS + 2; ++r) {
    const int off = __builtin_amdgcn_readfirstlane(rowbase + r * CROW);
    const float* cr = coef + off;        // SGPR (scalar) loads, K$-resident
    const int tlo = (r - 2 > 0) ? (r - 2) : 0;
    const int thi = (r < TS - 1) ? r : (TS - 1);
#pragma unroll
    for (int tl = tlo; tl <= thi; ++tl) {
      const int j = r - tl;              // 0..2, compile-time after unroll
#pragma unroll
      for (int i = 0; i < CROW; ++i)
        acc[tl] += cr[i] * Gr[j * CROW + i];
    }
  }

  __shared__ float aT[TS][DD + 1];
  __shared__ float musd[TS][2];
#pragma unroll
  for (int tl = 0; tl < TS; ++tl) aT[tl][e] = acc[tl];
  __syncthreads();
  {
    const int tg = e >> 4, g = e & 15;
    float s = 0.f, ss = 0.f;
#pragma unroll
    for (int k = 0; k < 16; ++k) {
      const float v = aT[tg][g * 16 + ((k + g) & 15)];
      s += v; ss += v * v;
    }
#pragma unroll
    for (int m = 8; m; m >>= 1) { s += __shfl_xor(s, m); ss += __shfl_xor(ss, m); }
    if (g == 0) {
      const float mu  = s * (1.f / DD);
      const float var = ss * (1.f / DD) - mu * mu;
      musd[tg][0] = mu;
      musd[tg][1] = rsqrtf(var + 1e-5f);
    }
  }
  __syncthreads();
#pragma unroll
  for (int tl = 0; tl < TS; ++tl) {
    const float mu = musd[tl][0], rs = musd[tl][1];
    out[((size_t)b * TT + t0 + tl) * DD + e] = (acc[tl] - mu) * rs * lw + lb;
  }
}

extern "C" void kernel_launch(void* const* d_in, const int* in_sizes, int n_in,
                              void* d_out, int out_size, void* d_ws, size_t ws_size,
                              hipStream_t stream) {
  const float* barX    = (const float*)d_in[0];
  const float* W       = (const float*)d_in[1];
  const float* phi_v_w = (const float*)d_in[2];
  const float* phi_v_b = (const float*)d_in[3];
  const float* phi_a_w = (const float*)d_in[4];
  const float* phi_a_b = (const float*)d_in[5];
  const float* gamma_v = (const float*)d_in[6];
  const float* gamma_a = (const float*)d_in[7];
  const float* WM_w    = (const float*)d_in[8];
  const float* WM_b    = (const float*)d_in[9];
  const float* dw_w    = (const float*)d_in[10];
  const float* dw_b    = (const float*)d_in[11];
  const float* pw_w    = (const float*)d_in[12];
  const float* pw_b    = (const float*)d_in[13];
  const float* ln_w    = (const float*)d_in[14];
  const float* ln_b    = (const float*)d_in[15];
  float* out = (float*)d_out;

  float* ws    = (float*)d_ws;
  float* Gt    = ws;            // 48*256 = 12288
  float* baset = ws + 12288;    // 256
  float* coef  = ws + 16384;    // 8*1026*16 = 131328 floats

  hipLaunchKernelGGL(ka_tables_coef, dim3(NTB + NBT / 16), dim3(256), 0, stream,
                     barX, W, phi_v_w, phi_v_b, phi_a_w, phi_a_b,
                     gamma_v, gamma_a, WM_w, WM_b, dw_w, dw_b, pw_w, pw_b,
                     Gt, baset, coef);
  hipLaunchKernelGGL(kb_main, dim3(BB * (TT / TS)), dim3(256), 0, stream,
                     coef, Gt, baset, ln_w, ln_b, out);
}